// Round 2
// baseline (3208.219 us; speedup 1.0000x reference)
//
#include <hip/hip_runtime.h>

#define N_NODES 100000
#define N_EDGES 3200000
#define IN_DIM 128
#define HID_DIM 64
#define OUT_DIM 2
#define N_GRAPHS 512

// ---- degree histogram over col (deg buffer pre-zeroed) -------------------
__global__ __launch_bounds__(256) void k_deg(const int* __restrict__ col,
                                             float* __restrict__ deg) {
    int e = blockIdx.x * 256 + threadIdx.x;
    if (e < N_EDGES) atomicAdd(&deg[col[e]], 1.0f);
}

// ---- dinv = rsqrt(deg + 1) in place (self-loop adds 1; always > 0) -------
__global__ __launch_bounds__(256) void k_dinv(float* __restrict__ deg) {
    int i = blockIdx.x * 256 + threadIdx.x;
    if (i < N_NODES) deg[i] = rsqrtf(deg[i] + 1.0f);
}

// ---- xw = x @ W_gcn  (100000x128 @ 128x64, fp32) -------------------------
// Block = 256 threads = 4 waves; wave handles 4 nodes; lane = output column.
// W staged to LDS (lane-consecutive reads; stride-1 over 64 lanes = 2-way
// bank alias, which is free on gfx950).
__global__ __launch_bounds__(256) void k_gemm(const float* __restrict__ x,
                                              const float* __restrict__ Wg,
                                              float* __restrict__ xw) {
    __shared__ float wl[IN_DIM * HID_DIM];  // 32 KB
    for (int i = threadIdx.x; i < IN_DIM * HID_DIM; i += 256) wl[i] = Wg[i];
    __syncthreads();

    int wave = threadIdx.x >> 6;
    int lane = threadIdx.x & 63;
    int node0 = blockIdx.x * 16 + wave * 4;   // 100000 = 6250 * 16, exact
    const float* xb = x + (size_t)node0 * IN_DIM;

    float acc[4] = {0.f, 0.f, 0.f, 0.f};
    for (int k0 = 0; k0 < IN_DIM; k0 += 4) {
        float4 xv[4];
#pragma unroll
        for (int m = 0; m < 4; m++) {
            xv[m] = *(const float4*)(xb + m * IN_DIM + k0);  // broadcast load
        }
#pragma unroll
        for (int t = 0; t < 4; t++) {
            float wv = wl[(k0 + t) * HID_DIM + lane];
#pragma unroll
            for (int m = 0; m < 4; m++) {
                float xs = (t == 0) ? xv[m].x : (t == 1) ? xv[m].y : (t == 2) ? xv[m].z : xv[m].w;
                acc[m] += xs * wv;
            }
        }
    }
#pragma unroll
    for (int m = 0; m < 4; m++) xw[(size_t)(node0 + m) * HID_DIM + lane] = acc[m];
}

// ---- z init with self-loop contribution: z[i] = xw[i] * dinv[i]^2 --------
__global__ __launch_bounds__(256) void k_self(const float4* __restrict__ xw4,
                                              const float* __restrict__ dinv,
                                              float4* __restrict__ z4) {
    int idx = blockIdx.x * 256 + threadIdx.x;  // 1.6M exact
    if (idx >= N_NODES * HID_DIM / 4) return;
    int node = idx >> 4;                       // 16 float4 per node row
    float d = dinv[node];
    float s = d * d;
    float4 v = xw4[idx];
    z4[idx] = make_float4(v.x * s, v.y * s, v.z * s, v.w * s);
}

// ---- edge scatter: z[col] += xw[row] * dinv[row]*dinv[col] ---------------
// 16 threads per edge, each handles 4 contiguous cols (float4 gather + 4 atomics).
__global__ __launch_bounds__(256) void k_edges(const int* __restrict__ row,
                                               const int* __restrict__ col,
                                               const float* __restrict__ dinv,
                                               const float4* __restrict__ xw4,
                                               float* __restrict__ z) {
    unsigned int tid = blockIdx.x * 256u + threadIdx.x;
    int e = (int)(tid >> 4);
    if (e >= N_EDGES) return;
    int q = (int)(tid & 15u);
    int r = row[e];
    int c = col[e];
    float w = dinv[r] * dinv[c];
    float4 v = xw4[r * 16 + q];
    float* zp = z + c * 64 + q * 4;
    atomicAdd(zp + 0, v.x * w);
    atomicAdd(zp + 1, v.y * w);
    atomicAdd(zp + 2, v.z * w);
    atomicAdd(zp + 3, v.w * w);
}

// ---- pool (mean over sorted batch, via binary search) + MLP + sigmoid ----
// One block (1 wave, 64 threads) per graph; thread j owns hidden column j.
__device__ inline int lower_bound_i(const int* __restrict__ a, int n, int v) {
    int lo = 0, hi = n;
    while (lo < hi) {
        int mid = (lo + hi) >> 1;
        if (a[mid] < v) lo = mid + 1; else hi = mid;
    }
    return lo;
}

__global__ __launch_bounds__(64) void k_pool_mlp(const float* __restrict__ z,
                                                 const int* __restrict__ batch,
                                                 const float* __restrict__ bg,
                                                 const float* __restrict__ W1,
                                                 const float* __restrict__ b1,
                                                 const float* __restrict__ W2,
                                                 const float* __restrict__ b2,
                                                 float* __restrict__ out) {
    int g = blockIdx.x;
    int j = threadIdx.x;
    int start = lower_bound_i(batch, N_NODES, g);
    int end   = lower_bound_i(batch, N_NODES, g + 1);

    float bgj = bg[j];
    float acc = 0.f;
    for (int n = start; n < end; n++) {
        acc += fmaxf(z[(size_t)n * 64 + j] + bgj, 0.f);  // ReLU(z + b_gcn), then sum
    }
    float cnt = (float)((end - start) > 0 ? (end - start) : 1);

    __shared__ float gs[64];
    __shared__ float hs[64];
    gs[j] = acc / cnt;
    __syncthreads();

    float h = b1[j];
    for (int k = 0; k < 64; k++) h += gs[k] * W1[k * 64 + j];
    hs[j] = fmaxf(h, 0.f);
    __syncthreads();

    if (j < OUT_DIM) {
        float o = b2[j];
        for (int k = 0; k < 64; k++) o += hs[k] * W2[k * OUT_DIM + j];
        o = 1.f / (1.f + expf(-o));
        out[g * OUT_DIM + j] = o;
    }
}

extern "C" void kernel_launch(void* const* d_in, const int* in_sizes, int n_in,
                              void* d_out, int out_size, void* d_ws, size_t ws_size,
                              hipStream_t stream) {
    const float* x   = (const float*)d_in[0];
    const int* eidx  = (const int*)d_in[1];
    const int* batch = (const int*)d_in[2];
    const float* Wg  = (const float*)d_in[3];
    const float* bg  = (const float*)d_in[4];
    const float* W1  = (const float*)d_in[5];
    const float* b1  = (const float*)d_in[6];
    const float* W2  = (const float*)d_in[7];
    const float* b2  = (const float*)d_in[8];
    float* out = (float*)d_out;

    // workspace layout: xw (25.6MB) | z (25.6MB) | deg->dinv (0.4MB)
    float* xw   = (float*)d_ws;
    float* z    = xw + (size_t)N_NODES * HID_DIM;
    float* dinv = z + (size_t)N_NODES * HID_DIM;

    const int* rowp = eidx;             // edge_index[0]
    const int* colp = eidx + N_EDGES;   // edge_index[1]

    hipMemsetAsync(dinv, 0, N_NODES * sizeof(float), stream);
    k_deg<<<(N_EDGES + 255) / 256, 256, 0, stream>>>(colp, dinv);
    k_dinv<<<(N_NODES + 255) / 256, 256, 0, stream>>>(dinv);
    k_gemm<<<N_NODES / 16, 256, 0, stream>>>(x, Wg, xw);
    k_self<<<(N_NODES * HID_DIM / 4) / 256, 256, 0, stream>>>((const float4*)xw, dinv, (float4*)z);
    k_edges<<<(int)(((long long)N_EDGES * 16) / 256), 256, 0, stream>>>(rowp, colp, dinv,
                                                                        (const float4*)xw, z);
    k_pool_mlp<<<N_GRAPHS, 64, 0, stream>>>(z, batch, bg, W1, b1, W2, b2, out);
}

// Round 3
// 864.906 us; speedup vs baseline: 3.7093x; 3.7093x over previous
//
#include <hip/hip_runtime.h>

#define N_NODES 100000
#define N_EDGES 3200000
#define IN_DIM 128
#define HID_DIM 64
#define OUT_DIM 2
#define N_GRAPHS 512
#define SCAN_B 1024
#define NB1 98   // ceil(100000/1024)

__device__ inline float uaf(unsigned int u) {
    union { unsigned int i; float f; } v; v.i = u; return v.f;
}
__device__ inline unsigned int fau(float f) {
    union { float f; unsigned int i; } v; v.f = f; return v.i;
}

// ---- in-degree count over col (cnt pre-zeroed) ---------------------------
__global__ __launch_bounds__(256) void k_count(const int* __restrict__ col,
                                               int* __restrict__ cnt) {
    int e = blockIdx.x * 256 + threadIdx.x;
    if (e < N_EDGES) atomicAdd(&cnt[col[e]], 1);
}

// ---- dinv = rsqrt(cnt + 1) (self-loop adds 1; always > 0) ----------------
__global__ __launch_bounds__(256) void k_dinv(const int* __restrict__ cnt,
                                              float* __restrict__ dinv) {
    int i = blockIdx.x * 256 + threadIdx.x;
    if (i < N_NODES) dinv[i] = rsqrtf((float)cnt[i] + 1.0f);
}

// ---- block-level exclusive scan of cnt -> rowptr (local), blocksum -------
__global__ __launch_bounds__(SCAN_B) void k_scan1(const int* __restrict__ cnt,
                                                  int* __restrict__ rowptr,
                                                  int* __restrict__ blocksum) {
    __shared__ int lds[SCAN_B];
    int i = blockIdx.x * SCAN_B + threadIdx.x;
    int v = (i < N_NODES) ? cnt[i] : 0;
    lds[threadIdx.x] = v;
    __syncthreads();
    for (int off = 1; off < SCAN_B; off <<= 1) {
        int t = (threadIdx.x >= off) ? lds[threadIdx.x - off] : 0;
        __syncthreads();
        lds[threadIdx.x] += t;
        __syncthreads();
    }
    if (i < N_NODES) rowptr[i] = lds[threadIdx.x] - v;  // local exclusive
    if (threadIdx.x == SCAN_B - 1) blocksum[blockIdx.x] = lds[SCAN_B - 1];
}

// ---- scan the 98 block sums (one block of 128) ---------------------------
__global__ __launch_bounds__(128) void k_scan2(const int* __restrict__ blocksum,
                                               int* __restrict__ blockoff) {
    __shared__ int lds[128];
    int v = (threadIdx.x < NB1) ? blocksum[threadIdx.x] : 0;
    lds[threadIdx.x] = v;
    __syncthreads();
    for (int off = 1; off < 128; off <<= 1) {
        int t = (threadIdx.x >= off) ? lds[threadIdx.x - off] : 0;
        __syncthreads();
        lds[threadIdx.x] += t;
        __syncthreads();
    }
    blockoff[threadIdx.x] = lds[threadIdx.x] - v;  // exclusive
}

// ---- add block offsets; produce final rowptr and cursor copy -------------
__global__ __launch_bounds__(SCAN_B) void k_scan3(int* __restrict__ rowptr,
                                                  const int* __restrict__ blockoff,
                                                  int* __restrict__ cursor) {
    int i = blockIdx.x * SCAN_B + threadIdx.x;
    if (i < N_NODES) {
        int p = rowptr[i] + blockoff[blockIdx.x];
        rowptr[i] = p;
        cursor[i] = p;
    }
    if (blockIdx.x == 0 && threadIdx.x == 0) rowptr[N_NODES] = N_EDGES;
}

// ---- fill CSR: csr[pos] = row, pos assigned per destination --------------
__global__ __launch_bounds__(256) void k_fill(const int* __restrict__ row,
                                              const int* __restrict__ col,
                                              int* __restrict__ cursor,
                                              int* __restrict__ csr) {
    int e = blockIdx.x * 256 + threadIdx.x;
    if (e < N_EDGES) {
        int pos = atomicAdd(&cursor[col[e]], 1);
        csr[pos] = row[e];
    }
}

// ---- xw = x @ W_gcn  (100000x128 @ 128x64, fp32) -------------------------
__global__ __launch_bounds__(256) void k_gemm(const float* __restrict__ x,
                                              const float* __restrict__ Wg,
                                              float* __restrict__ xw) {
    __shared__ float wl[IN_DIM * HID_DIM];  // 32 KB
    for (int i = threadIdx.x; i < IN_DIM * HID_DIM; i += 256) wl[i] = Wg[i];
    __syncthreads();

    int wave = threadIdx.x >> 6;
    int lane = threadIdx.x & 63;
    int node0 = blockIdx.x * 16 + wave * 4;   // 100000 = 6250 * 16, exact
    const float* xb = x + (size_t)node0 * IN_DIM;

    float acc[4] = {0.f, 0.f, 0.f, 0.f};
    for (int k0 = 0; k0 < IN_DIM; k0 += 4) {
        float4 xv[4];
#pragma unroll
        for (int m = 0; m < 4; m++) xv[m] = *(const float4*)(xb + m * IN_DIM + k0);
#pragma unroll
        for (int t = 0; t < 4; t++) {
            float wv = wl[(k0 + t) * HID_DIM + lane];
#pragma unroll
            for (int m = 0; m < 4; m++) {
                float xs = (t == 0) ? xv[m].x : (t == 1) ? xv[m].y : (t == 2) ? xv[m].z : xv[m].w;
                acc[m] += xs * wv;
            }
        }
    }
#pragma unroll
    for (int m = 0; m < 4; m++) xw[(size_t)(node0 + m) * HID_DIM + lane] = acc[m];
}

// ---- gather-aggregate + bias + ReLU + fused mean-pool partial sums -------
// One wave per node; lane = hidden column. Edge row ids broadcast via
// v_readlane (scalar pipe) -> per edge: 1 coalesced 256B wave load + 1 FMA.
// z[n] = dinv[n] * (sum_r dinv[r]*xw[r] + dinv[n]*xw[n]); val = relu(z+bg).
// Pool: block of 4 consecutive nodes (batch sorted) -> combined atomic when
// all 4 nodes share a graph (~98% of blocks), else per-wave atomics.
__global__ __launch_bounds__(256) void k_aggr(const float* __restrict__ xw,
                                              const int* __restrict__ rowptr,
                                              const int* __restrict__ csr,
                                              const float* __restrict__ dinv,
                                              const int* __restrict__ batch,
                                              const float* __restrict__ bg,
                                              float* __restrict__ gsum) {
    int wave = threadIdx.x >> 6;
    int lane = threadIdx.x & 63;
    int n = blockIdx.x * 4 + wave;           // 25000 blocks exact
    float dn = dinv[n];
    float acc0 = xw[(size_t)n * 64 + lane] * dn;   // self term (x dn at end)
    float acc1 = 0.f;
    int s = rowptr[n], e = rowptr[n + 1];

    for (int base = s; base < e; base += 64) {
        int rem = e - base;
        int idx = base + lane;
        int r = csr[idx < e ? idx : (e - 1)];
        float dr = dinv[r];
        if (rem >= 64) {
#pragma unroll
            for (int j = 0; j < 64; j += 2) {
                int r0 = __builtin_amdgcn_readlane(r, j);
                int r1 = __builtin_amdgcn_readlane(r, j + 1);
                float w0 = uaf(__builtin_amdgcn_readlane(fau(dr), j));
                float w1 = uaf(__builtin_amdgcn_readlane(fau(dr), j + 1));
                acc0 += xw[(size_t)r0 * 64 + lane] * w0;
                acc1 += xw[(size_t)r1 * 64 + lane] * w1;
            }
        } else {
            int j = 0;
            for (; j + 1 < rem; j += 2) {
                int r0 = __builtin_amdgcn_readlane(r, j);
                int r1 = __builtin_amdgcn_readlane(r, j + 1);
                float w0 = uaf(__builtin_amdgcn_readlane(fau(dr), j));
                float w1 = uaf(__builtin_amdgcn_readlane(fau(dr), j + 1));
                acc0 += xw[(size_t)r0 * 64 + lane] * w0;
                acc1 += xw[(size_t)r1 * 64 + lane] * w1;
            }
            if (j < rem) {
                int r0 = __builtin_amdgcn_readlane(r, j);
                float w0 = uaf(__builtin_amdgcn_readlane(fau(dr), j));
                acc0 += xw[(size_t)r0 * 64 + lane] * w0;
            }
        }
    }
    float val = fmaxf((acc0 + acc1) * dn + bg[lane], 0.f);

    int g = batch[n];
    __shared__ float sval[256];
    __shared__ int sg[4];
    sval[threadIdx.x] = val;
    if (lane == 0) sg[wave] = g;
    __syncthreads();
    bool uni = (sg[0] == sg[3]);
    if (uni) {
        if (wave == 0) {
            float t = sval[lane] + sval[64 + lane] + sval[128 + lane] + sval[192 + lane];
            atomicAdd(&gsum[sg[0] * 64 + lane], t);
        }
    } else {
        atomicAdd(&gsum[g * 64 + lane], val);
    }
}

// ---- divide by counts + MLP + sigmoid (one wave per graph) ---------------
__device__ inline int lower_bound_i(const int* __restrict__ a, int n, int v) {
    int lo = 0, hi = n;
    while (lo < hi) {
        int mid = (lo + hi) >> 1;
        if (a[mid] < v) lo = mid + 1; else hi = mid;
    }
    return lo;
}

__global__ __launch_bounds__(64) void k_mlp(const float* __restrict__ gsum,
                                            const int* __restrict__ batch,
                                            const float* __restrict__ W1,
                                            const float* __restrict__ b1,
                                            const float* __restrict__ W2,
                                            const float* __restrict__ b2,
                                            float* __restrict__ out) {
    int g = blockIdx.x;
    int j = threadIdx.x;
    int start = lower_bound_i(batch, N_NODES, g);
    int end   = lower_bound_i(batch, N_NODES, g + 1);
    float cnt = fmaxf((float)(end - start), 1.0f);

    __shared__ float gs[64];
    __shared__ float hs[64];
    gs[j] = gsum[g * 64 + j] / cnt;
    __syncthreads();

    float h = b1[j];
    for (int k = 0; k < 64; k++) h += gs[k] * W1[k * 64 + j];
    hs[j] = fmaxf(h, 0.f);
    __syncthreads();

    if (j < OUT_DIM) {
        float o = b2[j];
        for (int k = 0; k < 64; k++) o += hs[k] * W2[k * OUT_DIM + j];
        out[g * OUT_DIM + j] = 1.f / (1.f + expf(-o));
    }
}

extern "C" void kernel_launch(void* const* d_in, const int* in_sizes, int n_in,
                              void* d_out, int out_size, void* d_ws, size_t ws_size,
                              hipStream_t stream) {
    const float* x   = (const float*)d_in[0];
    const int* eidx  = (const int*)d_in[1];
    const int* batch = (const int*)d_in[2];
    const float* Wg  = (const float*)d_in[3];
    const float* bg  = (const float*)d_in[4];
    const float* W1  = (const float*)d_in[5];
    const float* b1  = (const float*)d_in[6];
    const float* W2  = (const float*)d_in[7];
    const float* b2  = (const float*)d_in[8];
    float* out = (float*)d_out;

    // workspace layout (bytes): all 4B-aligned
    char* w = (char*)d_ws;
    float* xw      = (float*)w;                 w += (size_t)N_NODES * HID_DIM * 4;  // 25.6 MB
    float* dinv    = (float*)w;                 w += N_NODES * 4;
    int*   cnt     = (int*)w;                   w += N_NODES * 4;
    int*   rowptr  = (int*)w;                   w += (N_NODES + 2) * 4;
    int*   cursor  = (int*)w;                   w += N_NODES * 4;
    int*   blocksum= (int*)w;                   w += 512;
    int*   blockoff= (int*)w;                   w += 512;
    int*   csr     = (int*)w;                   w += (size_t)N_EDGES * 4;            // 12.8 MB
    float* gsum    = (float*)w;                 w += N_GRAPHS * HID_DIM * 4;         // 131 KB

    const int* rowp = eidx;             // edge_index[0] (sources)
    const int* colp = eidx + N_EDGES;   // edge_index[1] (destinations)

    hipMemsetAsync(cnt, 0, N_NODES * sizeof(int), stream);
    hipMemsetAsync(gsum, 0, N_GRAPHS * HID_DIM * sizeof(float), stream);

    k_count<<<(N_EDGES + 255) / 256, 256, 0, stream>>>(colp, cnt);
    k_dinv<<<(N_NODES + 255) / 256, 256, 0, stream>>>(cnt, dinv);
    k_scan1<<<NB1, SCAN_B, 0, stream>>>(cnt, rowptr, blocksum);
    k_scan2<<<1, 128, 0, stream>>>(blocksum, blockoff);
    k_scan3<<<NB1, SCAN_B, 0, stream>>>(rowptr, blockoff, cursor);
    k_fill<<<(N_EDGES + 255) / 256, 256, 0, stream>>>(rowp, colp, cursor, csr);
    k_gemm<<<N_NODES / 16, 256, 0, stream>>>(x, Wg, xw);
    k_aggr<<<N_NODES / 4, 256, 0, stream>>>(xw, rowptr, csr, dinv, batch, bg, gsum);
    k_mlp<<<N_GRAPHS, 64, 0, stream>>>(gsum, batch, W1, b1, W2, b2, out);
}

// Round 4
// 647.377 us; speedup vs baseline: 4.9557x; 1.3360x over previous
//
#include <hip/hip_runtime.h>

#define N_NODES 100000
#define N_EDGES 3200000
#define IN_DIM 128
#define HID_DIM 64
#define OUT_DIM 2
#define N_GRAPHS 512
#define SCAN_B 1024
#define NB1 98   // ceil(100000/1024)

__device__ inline float uaf(unsigned int u) {
    union { unsigned int i; float f; } v; v.i = u; return v.f;
}
__device__ inline unsigned int fau(float f) {
    union { float f; unsigned int i; } v; v.f = f; return v.i;
}

// ---- in-degree count over col; rank[e] = this edge's slot within its dest
__global__ __launch_bounds__(256) void k_count(const int* __restrict__ col,
                                               int* __restrict__ cnt,
                                               int* __restrict__ rank) {
    int e = blockIdx.x * 256 + threadIdx.x;
    if (e < N_EDGES) rank[e] = atomicAdd(&cnt[col[e]], 1);
}

// ---- block-level exclusive scan of cnt -> rowptr (local), blocksum; dinv fused
__global__ __launch_bounds__(SCAN_B) void k_scan1(const int* __restrict__ cnt,
                                                  int* __restrict__ rowptr,
                                                  int* __restrict__ blocksum,
                                                  float* __restrict__ dinv) {
    __shared__ int lds[SCAN_B];
    int i = blockIdx.x * SCAN_B + threadIdx.x;
    int v = (i < N_NODES) ? cnt[i] : 0;
    lds[threadIdx.x] = v;
    __syncthreads();
    for (int off = 1; off < SCAN_B; off <<= 1) {
        int t = (threadIdx.x >= off) ? lds[threadIdx.x - off] : 0;
        __syncthreads();
        lds[threadIdx.x] += t;
        __syncthreads();
    }
    if (i < N_NODES) {
        rowptr[i] = lds[threadIdx.x] - v;  // local exclusive
        dinv[i] = rsqrtf((float)v + 1.0f); // self-loop adds 1
    }
    if (threadIdx.x == SCAN_B - 1) blocksum[blockIdx.x] = lds[SCAN_B - 1];
}

// ---- scan the 98 block sums (one block of 128) ---------------------------
__global__ __launch_bounds__(128) void k_scan2(const int* __restrict__ blocksum,
                                               int* __restrict__ blockoff) {
    __shared__ int lds[128];
    int v = (threadIdx.x < NB1) ? blocksum[threadIdx.x] : 0;
    lds[threadIdx.x] = v;
    __syncthreads();
    for (int off = 1; off < 128; off <<= 1) {
        int t = (threadIdx.x >= off) ? lds[threadIdx.x - off] : 0;
        __syncthreads();
        lds[threadIdx.x] += t;
        __syncthreads();
    }
    blockoff[threadIdx.x] = lds[threadIdx.x] - v;  // exclusive
}

// ---- add block offsets; produce final rowptr ------------------------------
__global__ __launch_bounds__(SCAN_B) void k_scan3(int* __restrict__ rowptr,
                                                  const int* __restrict__ blockoff) {
    int i = blockIdx.x * SCAN_B + threadIdx.x;
    if (i < N_NODES) rowptr[i] += blockoff[blockIdx.x];
    if (blockIdx.x == 0 && threadIdx.x == 0) rowptr[N_NODES] = N_EDGES;
}

// ---- fill CSR, atomic-free: pos = rowptr[col] + rank --------------------
__global__ __launch_bounds__(256) void k_fill(const int* __restrict__ row,
                                              const int* __restrict__ col,
                                              const int* __restrict__ rowptr,
                                              const int* __restrict__ rank,
                                              int* __restrict__ csr) {
    int e = blockIdx.x * 256 + threadIdx.x;
    if (e < N_EDGES) {
        csr[rowptr[col[e]] + rank[e]] = row[e];
    }
}

// ---- xw = x @ W_gcn  (100000x128 @ 128x64, fp32) -------------------------
__global__ __launch_bounds__(256) void k_gemm(const float* __restrict__ x,
                                              const float* __restrict__ Wg,
                                              float* __restrict__ xw) {
    __shared__ float wl[IN_DIM * HID_DIM];  // 32 KB
    for (int i = threadIdx.x; i < IN_DIM * HID_DIM; i += 256) wl[i] = Wg[i];
    __syncthreads();

    int wave = threadIdx.x >> 6;
    int lane = threadIdx.x & 63;
    int node0 = blockIdx.x * 16 + wave * 4;   // 100000 = 6250 * 16, exact
    const float* xb = x + (size_t)node0 * IN_DIM;

    float acc[4] = {0.f, 0.f, 0.f, 0.f};
    for (int k0 = 0; k0 < IN_DIM; k0 += 4) {
        float4 xv[4];
#pragma unroll
        for (int m = 0; m < 4; m++) xv[m] = *(const float4*)(xb + m * IN_DIM + k0);
#pragma unroll
        for (int t = 0; t < 4; t++) {
            float wv = wl[(k0 + t) * HID_DIM + lane];
#pragma unroll
            for (int m = 0; m < 4; m++) {
                float xs = (t == 0) ? xv[m].x : (t == 1) ? xv[m].y : (t == 2) ? xv[m].z : xv[m].w;
                acc[m] += xs * wv;
            }
        }
    }
#pragma unroll
    for (int m = 0; m < 4; m++) xw[(size_t)(node0 + m) * HID_DIM + lane] = acc[m];
}

// ---- gather-aggregate + bias + ReLU + fused mean-pool partial sums -------
__global__ __launch_bounds__(256) void k_aggr(const float* __restrict__ xw,
                                              const int* __restrict__ rowptr,
                                              const int* __restrict__ csr,
                                              const float* __restrict__ dinv,
                                              const int* __restrict__ batch,
                                              const float* __restrict__ bg,
                                              float* __restrict__ gsum) {
    int wave = threadIdx.x >> 6;
    int lane = threadIdx.x & 63;
    int n = blockIdx.x * 4 + wave;           // 25000 blocks exact
    float dn = dinv[n];
    float acc0 = xw[(size_t)n * 64 + lane] * dn;   // self term (x dn at end)
    float acc1 = 0.f;
    int s = rowptr[n], e = rowptr[n + 1];

    for (int base = s; base < e; base += 64) {
        int rem = e - base;
        int idx = base + lane;
        int r = csr[idx < e ? idx : (e - 1)];
        float dr = dinv[r];
        if (rem >= 64) {
#pragma unroll
            for (int j = 0; j < 64; j += 2) {
                int r0 = __builtin_amdgcn_readlane(r, j);
                int r1 = __builtin_amdgcn_readlane(r, j + 1);
                float w0 = uaf(__builtin_amdgcn_readlane(fau(dr), j));
                float w1 = uaf(__builtin_amdgcn_readlane(fau(dr), j + 1));
                acc0 += xw[(size_t)r0 * 64 + lane] * w0;
                acc1 += xw[(size_t)r1 * 64 + lane] * w1;
            }
        } else {
            int j = 0;
            for (; j + 1 < rem; j += 2) {
                int r0 = __builtin_amdgcn_readlane(r, j);
                int r1 = __builtin_amdgcn_readlane(r, j + 1);
                float w0 = uaf(__builtin_amdgcn_readlane(fau(dr), j));
                float w1 = uaf(__builtin_amdgcn_readlane(fau(dr), j + 1));
                acc0 += xw[(size_t)r0 * 64 + lane] * w0;
                acc1 += xw[(size_t)r1 * 64 + lane] * w1;
            }
            if (j < rem) {
                int r0 = __builtin_amdgcn_readlane(r, j);
                float w0 = uaf(__builtin_amdgcn_readlane(fau(dr), j));
                acc0 += xw[(size_t)r0 * 64 + lane] * w0;
            }
        }
    }
    float val = fmaxf((acc0 + acc1) * dn + bg[lane], 0.f);

    int g = batch[n];
    __shared__ float sval[256];
    __shared__ int sg[4];
    sval[threadIdx.x] = val;
    if (lane == 0) sg[wave] = g;
    __syncthreads();
    bool uni = (sg[0] == sg[3]);
    if (uni) {
        if (wave == 0) {
            float t = sval[lane] + sval[64 + lane] + sval[128 + lane] + sval[192 + lane];
            atomicAdd(&gsum[sg[0] * 64 + lane], t);
        }
    } else {
        atomicAdd(&gsum[g * 64 + lane], val);
    }
}

// ---- divide by counts + MLP + sigmoid (one wave per graph) ---------------
__device__ inline int lower_bound_i(const int* __restrict__ a, int n, int v) {
    int lo = 0, hi = n;
    while (lo < hi) {
        int mid = (lo + hi) >> 1;
        if (a[mid] < v) lo = mid + 1; else hi = mid;
    }
    return lo;
}

__global__ __launch_bounds__(64) void k_mlp(const float* __restrict__ gsum,
                                            const int* __restrict__ batch,
                                            const float* __restrict__ W1,
                                            const float* __restrict__ b1,
                                            const float* __restrict__ W2,
                                            const float* __restrict__ b2,
                                            float* __restrict__ out) {
    int g = blockIdx.x;
    int j = threadIdx.x;
    int start = lower_bound_i(batch, N_NODES, g);
    int end   = lower_bound_i(batch, N_NODES, g + 1);
    float cnt = fmaxf((float)(end - start), 1.0f);

    __shared__ float gs[64];
    __shared__ float hs[64];
    gs[j] = gsum[g * 64 + j] / cnt;
    __syncthreads();

    float h = b1[j];
    for (int k = 0; k < 64; k++) h += gs[k] * W1[k * 64 + j];
    hs[j] = fmaxf(h, 0.f);
    __syncthreads();

    if (j < OUT_DIM) {
        float o = b2[j];
        for (int k = 0; k < 64; k++) o += hs[k] * W2[k * OUT_DIM + j];
        out[g * OUT_DIM + j] = 1.f / (1.f + expf(-o));
    }
}

extern "C" void kernel_launch(void* const* d_in, const int* in_sizes, int n_in,
                              void* d_out, int out_size, void* d_ws, size_t ws_size,
                              hipStream_t stream) {
    const float* x   = (const float*)d_in[0];
    const int* eidx  = (const int*)d_in[1];
    const int* batch = (const int*)d_in[2];
    const float* Wg  = (const float*)d_in[3];
    const float* bg  = (const float*)d_in[4];
    const float* W1  = (const float*)d_in[5];
    const float* b1  = (const float*)d_in[6];
    const float* W2  = (const float*)d_in[7];
    const float* b2  = (const float*)d_in[8];
    float* out = (float*)d_out;

    // workspace layout. rank aliases the first half of xw: rank is dead after
    // k_fill, and k_gemm (which writes xw) launches after k_fill on the same
    // stream. Total footprint ~39.8 MB (within proven budget).
    char* w = (char*)d_ws;
    float* xw      = (float*)w;
    int*   rank    = (int*)w;                   w += (size_t)N_NODES * HID_DIM * 4;  // 25.6 MB
    int*   csr     = (int*)w;                   w += (size_t)N_EDGES * 4;            // 12.8 MB
    float* dinv    = (float*)w;                 w += N_NODES * 4;
    int*   cnt     = (int*)w;                   w += N_NODES * 4;
    int*   rowptr  = (int*)w;                   w += (N_NODES + 2) * 4;
    int*   blocksum= (int*)w;                   w += 512;
    int*   blockoff= (int*)w;                   w += 512;
    float* gsum    = (float*)w;                 w += N_GRAPHS * HID_DIM * 4;         // 131 KB

    const int* rowp = eidx;             // edge_index[0] (sources)
    const int* colp = eidx + N_EDGES;   // edge_index[1] (destinations)

    hipMemsetAsync(cnt, 0, N_NODES * sizeof(int), stream);
    hipMemsetAsync(gsum, 0, N_GRAPHS * HID_DIM * sizeof(float), stream);

    k_count<<<(N_EDGES + 255) / 256, 256, 0, stream>>>(colp, cnt, rank);
    k_scan1<<<NB1, SCAN_B, 0, stream>>>(cnt, rowptr, blocksum, dinv);
    k_scan2<<<1, 128, 0, stream>>>(blocksum, blockoff);
    k_scan3<<<NB1, SCAN_B, 0, stream>>>(rowptr, blockoff);
    k_fill<<<(N_EDGES + 255) / 256, 256, 0, stream>>>(rowp, colp, rowptr, rank, csr);
    k_gemm<<<N_NODES / 16, 256, 0, stream>>>(x, Wg, xw);   // clobbers rank (dead)
    k_aggr<<<N_NODES / 4, 256, 0, stream>>>(xw, rowptr, csr, dinv, batch, bg, gsum);
    k_mlp<<<N_GRAPHS, 64, 0, stream>>>(gsum, batch, W1, b1, W2, b2, out);
}

// Round 5
// 423.069 us; speedup vs baseline: 7.5832x; 1.5302x over previous
//
#include <hip/hip_runtime.h>

#define N_NODES 100000
#define N_EDGES 3200000
#define IN_DIM 128
#define HID_DIM 64
#define OUT_DIM 2
#define N_GRAPHS 512
#define SCAN_B 1024
#define NB1 98          // ceil(100000/1024)
#define ZERO_ROW N_NODES  // reserved all-zero bf16 row for tail padding

__device__ inline float uaf(unsigned int u) {
    union { unsigned int i; float f; } v; v.i = u; return v.f;
}
__device__ inline unsigned int fau(float f) {
    union { float f; unsigned int i; } v; v.f = f; return v.i;
}
__device__ inline unsigned short f2bf(float f) {
    union { float f; unsigned int i; } v; v.f = f;
    unsigned int r = v.i + 0x7fffu + ((v.i >> 16) & 1u);
    return (unsigned short)(r >> 16);
}
__device__ inline float bf2f(unsigned short u) {
    union { unsigned int i; float f; } v; v.i = ((unsigned int)u) << 16; return v.f;
}

// ---- in-degree count over col; rank[e] = this edge's slot within its dest
__global__ __launch_bounds__(256) void k_count(const int* __restrict__ col,
                                               int* __restrict__ cnt,
                                               int* __restrict__ rank) {
    int e = blockIdx.x * 256 + threadIdx.x;
    if (e < N_EDGES) rank[e] = atomicAdd(&cnt[col[e]], 1);
}

// ---- block-level exclusive scan of cnt -> rowptr (local), blocksum; dinv fused
__global__ __launch_bounds__(SCAN_B) void k_scan1(const int* __restrict__ cnt,
                                                  int* __restrict__ rowptr,
                                                  int* __restrict__ blocksum,
                                                  float* __restrict__ dinv) {
    __shared__ int lds[SCAN_B];
    int i = blockIdx.x * SCAN_B + threadIdx.x;
    int v = (i < N_NODES) ? cnt[i] : 0;
    lds[threadIdx.x] = v;
    __syncthreads();
    for (int off = 1; off < SCAN_B; off <<= 1) {
        int t = (threadIdx.x >= off) ? lds[threadIdx.x - off] : 0;
        __syncthreads();
        lds[threadIdx.x] += t;
        __syncthreads();
    }
    if (i < N_NODES) {
        rowptr[i] = lds[threadIdx.x] - v;  // local exclusive
        dinv[i] = rsqrtf((float)v + 1.0f); // self-loop adds 1
    }
    if (threadIdx.x == SCAN_B - 1) blocksum[blockIdx.x] = lds[SCAN_B - 1];
}

// ---- finalize rowptr: each block re-scans the 98 block sums locally ------
__global__ __launch_bounds__(SCAN_B) void k_scan3(int* __restrict__ rowptr,
                                                  const int* __restrict__ blocksum) {
    __shared__ int lds[128];
    if (threadIdx.x < 128) {
        int v = (threadIdx.x < NB1) ? blocksum[threadIdx.x] : 0;
        lds[threadIdx.x] = v;
    }
    __syncthreads();
    // single-wave scan by thread 0..127 done serially-free via simple loop
    if (threadIdx.x == 0) {
        int run = 0;
        for (int b = 0; b < NB1; b++) { int t = lds[b]; lds[b] = run; run += t; }
    }
    __syncthreads();
    int i = blockIdx.x * SCAN_B + threadIdx.x;
    if (i < N_NODES) rowptr[i] += lds[blockIdx.x];
    if (blockIdx.x == 0 && threadIdx.x == 0) rowptr[N_NODES] = N_EDGES;
}

// ---- fill CSR, atomic-free: pos = rowptr[col] + rank ---------------------
__global__ __launch_bounds__(256) void k_fill(const int* __restrict__ row,
                                              const int* __restrict__ col,
                                              const int* __restrict__ rowptr,
                                              const int* __restrict__ rank,
                                              int* __restrict__ csr) {
    int e = blockIdx.x * 256 + threadIdx.x;
    if (e < N_EDGES) {
        csr[rowptr[col[e]] + rank[e]] = row[e];
    }
}

// ---- xws = (x @ W_gcn) * dinv, output bf16 -------------------------------
// Wave handles 8 nodes, lane = output col. x rows loaded coalesced into
// registers (16 independent 256B loads), broadcast via v_readlane (SGPR
// operand into v_fmac). W in LDS, ds_read_b32 stride-1 (2-way alias free).
__global__ __launch_bounds__(256) void k_gemm(const float* __restrict__ x,
                                              const float* __restrict__ Wg,
                                              const float* __restrict__ dinv,
                                              unsigned short* __restrict__ xws) {
    __shared__ float wl[IN_DIM * HID_DIM];  // 32 KB
    for (int i = threadIdx.x; i < IN_DIM * HID_DIM; i += 256) wl[i] = Wg[i];
    __syncthreads();

    int wave = threadIdx.x >> 6;
    int lane = threadIdx.x & 63;
    int node0 = blockIdx.x * 32 + wave * 8;   // 100000 = 3125 * 32, exact

    const int* xi = (const int*)x;
    int xr[8][2];
#pragma unroll
    for (int m = 0; m < 8; m++) {
#pragma unroll
        for (int h = 0; h < 2; h++)
            xr[m][h] = xi[(size_t)(node0 + m) * IN_DIM + h * 64 + lane];
    }

    float acc[8] = {0.f, 0.f, 0.f, 0.f, 0.f, 0.f, 0.f, 0.f};
#pragma unroll
    for (int k = 0; k < 64; k++) {
        float wv = wl[k * HID_DIM + lane];
#pragma unroll
        for (int m = 0; m < 8; m++)
            acc[m] += uaf(__builtin_amdgcn_readlane(xr[m][0], k)) * wv;
    }
#pragma unroll
    for (int k = 0; k < 64; k++) {
        float wv = wl[(64 + k) * HID_DIM + lane];
#pragma unroll
        for (int m = 0; m < 8; m++)
            acc[m] += uaf(__builtin_amdgcn_readlane(xr[m][1], k)) * wv;
    }

#pragma unroll
    for (int m = 0; m < 8; m++) {
        float dn = dinv[node0 + m];             // wave-uniform -> s_load
        xws[(size_t)(node0 + m) * HID_DIM + lane] = f2bf(acc[m] * dn);
    }
}

// ---- gather-aggregate + bias + ReLU + fused mean-pool partial sums -------
// z[n] = dinv[n] * (xws[n] + sum_edges xws[row]) + bg; val = relu(z).
// One wave per node; lane = col; bf16 rows (128 B gather per edge).
// Tail padding: lanes beyond the edge list point at the zero row.
__global__ __launch_bounds__(256) void k_aggr(const unsigned short* __restrict__ xws,
                                              const int* __restrict__ rowptr,
                                              const int* __restrict__ csr,
                                              const float* __restrict__ dinv,
                                              const int* __restrict__ batch,
                                              const float* __restrict__ bg,
                                              float* __restrict__ gsum) {
    int wave = threadIdx.x >> 6;
    int lane = threadIdx.x & 63;
    int n = blockIdx.x * 4 + wave;           // 25000 blocks exact
    float dn = dinv[n];
    float a0 = bf2f(xws[(size_t)n * HID_DIM + lane]);   // self term
    float a1 = 0.f, a2 = 0.f, a3 = 0.f;
    int s = rowptr[n], e = rowptr[n + 1];

    for (int base = s; base < e; base += 64) {
        int idx = base + lane;
        int r = ZERO_ROW;
        if (idx < e) r = csr[idx];
        int rem = e - base;
        int rounds = (rem < 64 ? rem : 64);
        rounds = (rounds + 3) & ~3;          // padded lanes hold ZERO_ROW
        for (int j = 0; j < rounds; j += 4) {
            int r0 = __builtin_amdgcn_readlane(r, j);
            int r1 = __builtin_amdgcn_readlane(r, j + 1);
            int r2 = __builtin_amdgcn_readlane(r, j + 2);
            int r3 = __builtin_amdgcn_readlane(r, j + 3);
            a0 += bf2f(xws[(size_t)r0 * HID_DIM + lane]);
            a1 += bf2f(xws[(size_t)r1 * HID_DIM + lane]);
            a2 += bf2f(xws[(size_t)r2 * HID_DIM + lane]);
            a3 += bf2f(xws[(size_t)r3 * HID_DIM + lane]);
        }
    }
    float val = fmaxf(((a0 + a1) + (a2 + a3)) * dn + bg[lane], 0.f);

    int g = batch[n];
    __shared__ float sval[256];
    __shared__ int sg[4];
    sval[threadIdx.x] = val;
    if (lane == 0) sg[wave] = g;
    __syncthreads();
    bool uni = (sg[0] == sg[3]);
    if (uni) {
        if (wave == 0) {
            float t = sval[lane] + sval[64 + lane] + sval[128 + lane] + sval[192 + lane];
            atomicAdd(&gsum[sg[0] * 64 + lane], t);
        }
    } else {
        atomicAdd(&gsum[g * 64 + lane], val);
    }
}

// ---- divide by counts + MLP + sigmoid (one wave per graph) ---------------
__device__ inline int lower_bound_i(const int* __restrict__ a, int n, int v) {
    int lo = 0, hi = n;
    while (lo < hi) {
        int mid = (lo + hi) >> 1;
        if (a[mid] < v) lo = mid + 1; else hi = mid;
    }
    return lo;
}

__global__ __launch_bounds__(64) void k_mlp(const float* __restrict__ gsum,
                                            const int* __restrict__ batch,
                                            const float* __restrict__ W1,
                                            const float* __restrict__ b1,
                                            const float* __restrict__ W2,
                                            const float* __restrict__ b2,
                                            float* __restrict__ out) {
    int g = blockIdx.x;
    int j = threadIdx.x;
    int start = lower_bound_i(batch, N_NODES, g);
    int end   = lower_bound_i(batch, N_NODES, g + 1);
    float cnt = fmaxf((float)(end - start), 1.0f);

    __shared__ float gs[64];
    __shared__ float hs[64];
    gs[j] = gsum[g * 64 + j] / cnt;
    __syncthreads();

    float h = b1[j];
    for (int k = 0; k < 64; k++) h += gs[k] * W1[k * 64 + j];
    hs[j] = fmaxf(h, 0.f);
    __syncthreads();

    if (j < OUT_DIM) {
        float o = b2[j];
        for (int k = 0; k < 64; k++) o += hs[k] * W2[k * OUT_DIM + j];
        out[g * OUT_DIM + j] = 1.f / (1.f + expf(-o));
    }
}

extern "C" void kernel_launch(void* const* d_in, const int* in_sizes, int n_in,
                              void* d_out, int out_size, void* d_ws, size_t ws_size,
                              hipStream_t stream) {
    const float* x   = (const float*)d_in[0];
    const int* eidx  = (const int*)d_in[1];
    const int* batch = (const int*)d_in[2];
    const float* Wg  = (const float*)d_in[3];
    const float* bg  = (const float*)d_in[4];
    const float* W1  = (const float*)d_in[5];
    const float* b1  = (const float*)d_in[6];
    const float* W2  = (const float*)d_in[7];
    const float* b2  = (const float*)d_in[8];
    float* out = (float*)d_out;

    // workspace layout. rank aliases xws (rank dead after k_fill; k_gemm
    // writes xws after k_fill on the same stream). ~27 MB total.
    char* w = (char*)d_ws;
    unsigned short* xws = (unsigned short*)w;
    int*   rank    = (int*)w;                   w += (size_t)(N_NODES + 1) * HID_DIM * 2; // 12.8 MB
    int*   csr     = (int*)w;                   w += (size_t)N_EDGES * 4;                 // 12.8 MB
    float* dinv    = (float*)w;                 w += N_NODES * 4;
    int*   cnt     = (int*)w;                   w += N_NODES * 4;
    int*   rowptr  = (int*)w;                   w += (N_NODES + 2) * 4;
    int*   blocksum= (int*)w;                   w += 512;
    float* gsum    = (float*)w;                 w += N_GRAPHS * HID_DIM * 4;              // 131 KB

    const int* rowp = eidx;             // edge_index[0] (sources)
    const int* colp = eidx + N_EDGES;   // edge_index[1] (destinations)

    hipMemsetAsync(cnt, 0, N_NODES * sizeof(int), stream);
    hipMemsetAsync(gsum, 0, N_GRAPHS * HID_DIM * sizeof(float), stream);

    k_count<<<(N_EDGES + 255) / 256, 256, 0, stream>>>(colp, cnt, rank);
    k_scan1<<<NB1, SCAN_B, 0, stream>>>(cnt, rowptr, blocksum, dinv);
    k_scan3<<<NB1, SCAN_B, 0, stream>>>(rowptr, blocksum);
    k_fill<<<(N_EDGES + 255) / 256, 256, 0, stream>>>(rowp, colp, rowptr, rank, csr);
    // zero the padding row AFTER k_fill (xws aliases rank)
    hipMemsetAsync(xws + (size_t)ZERO_ROW * HID_DIM, 0, HID_DIM * 2, stream);
    k_gemm<<<N_NODES / 32, 256, 0, stream>>>(x, Wg, dinv, xws);  // clobbers rank (dead)
    k_aggr<<<N_NODES / 4, 256, 0, stream>>>(xws, rowptr, csr, dinv, batch, bg, gsum);
    k_mlp<<<N_GRAPHS, 64, 0, stream>>>(gsum, batch, W1, b1, W2, b2, out);
}

// Round 6
// 364.582 us; speedup vs baseline: 8.7997x; 1.1604x over previous
//
#include <hip/hip_runtime.h>

#define N_NODES 100000
#define N_EDGES 3200000
#define IN_DIM 128
#define HID_DIM 64
#define OUT_DIM 2
#define N_GRAPHS 512

#define BSHIFT 7
#define NBUCK 782          // ceil(100000/128)
#define NB3 512            // blocks in hist/scatter passes
#define EPB 6250           // edges per block (512*6250 = 3.2M exact)
#define NSB 391            // scan blocks: 782*512/1024 = 391 exact
#define LDS_E 6144         // per-bucket edge capacity (mean 4096, sd 64)
#define ZERO_ROW N_NODES   // all-zero xws row used for 4-alignment padding

__device__ inline float uaf(unsigned int u) {
    union { unsigned int i; float f; } v; v.i = u; return v.f;
}
__device__ inline unsigned short f2bf(float f) {
    union { float f; unsigned int i; } v; v.f = f;
    unsigned int r = v.i + 0x7fffu + ((v.i >> 16) & 1u);
    return (unsigned short)(r >> 16);
}
__device__ inline float bf2f(unsigned short u) {
    union { unsigned int i; float f; } v; v.i = ((unsigned int)u) << 16; return v.f;
}

// ---- pass 1: per-block LDS histogram over 782 coarse buckets -------------
__global__ __launch_bounds__(256) void k_hist(const int* __restrict__ col,
                                              int* __restrict__ H) {
    __shared__ int h[NBUCK];
    for (int i = threadIdx.x; i < NBUCK; i += 256) h[i] = 0;
    __syncthreads();
    int b = blockIdx.x;
    int s = b * EPB, e = s + EPB;
    for (int i = s + threadIdx.x; i < e; i += 256)
        atomicAdd(&h[col[i] >> BSHIFT], 1);
    __syncthreads();
    for (int i = threadIdx.x; i < NBUCK; i += 256)
        H[i * NB3 + b] = h[i];                    // bucket-major for the scan
}

// ---- pass 2a: local exclusive scan of the 400384-entry matrix ------------
__global__ __launch_bounds__(1024) void k_scan_a(const int* __restrict__ H,
                                                 int* __restrict__ OFF,
                                                 int* __restrict__ bsum) {
    __shared__ int lds[1024];
    int i = blockIdx.x * 1024 + threadIdx.x;
    int v = H[i];
    lds[threadIdx.x] = v;
    __syncthreads();
    for (int off = 1; off < 1024; off <<= 1) {
        int t = (threadIdx.x >= off) ? lds[threadIdx.x - off] : 0;
        __syncthreads();
        lds[threadIdx.x] += t;
        __syncthreads();
    }
    OFF[i] = lds[threadIdx.x] - v;
    if (threadIdx.x == 1023) bsum[blockIdx.x] = lds[1023];
}

// ---- pass 2b: finalize with block-sum prefix ------------------------------
__global__ __launch_bounds__(1024) void k_scan_b(int* __restrict__ OFF,
                                                 const int* __restrict__ bsum) {
    __shared__ int ls[NSB];
    for (int i = threadIdx.x; i < NSB; i += 1024) ls[i] = bsum[i];
    __syncthreads();
    if (threadIdx.x == 0) {
        int run = 0;
        for (int b = 0; b < NSB; b++) { int t = ls[b]; ls[b] = run; run += t; }
    }
    __syncthreads();
    int i = blockIdx.x * 1024 + threadIdx.x;
    OFF[i] += ls[blockIdx.x];
}

// ---- pass 3: scatter packed edges into bucket-sorted order ---------------
// pk = (col & 127) << 17 | row   (row < 2^17). Per block, per bucket the
// writes are CONSECUTIVE slots -> write amplification collapses.
__global__ __launch_bounds__(256) void k_scatter(const int* __restrict__ row,
                                                 const int* __restrict__ col,
                                                 const int* __restrict__ OFF,
                                                 int* __restrict__ binned) {
    __shared__ int lofs[NBUCK];
    __shared__ int cur[NBUCK];
    int b = blockIdx.x;
    for (int i = threadIdx.x; i < NBUCK; i += 256) {
        lofs[i] = OFF[i * NB3 + b];
        cur[i] = 0;
    }
    __syncthreads();
    int s = b * EPB, e = s + EPB;
    for (int i = s + threadIdx.x; i < e; i += 256) {
        int c = col[i];
        int r = row[i];
        int bk = c >> BSHIFT;
        int rk = atomicAdd(&cur[bk], 1);
        binned[lofs[bk] + rk] = ((c & 127) << 17) | r;
    }
}

// ---- per-node degree + dinv from the binned array (LDS-local counts) -----
__global__ __launch_bounds__(256) void k_deg(const int* __restrict__ binned,
                                             const int* __restrict__ OFF,
                                             int* __restrict__ degs,
                                             float* __restrict__ dinv) {
    int bkt = blockIdx.x;
    int s = OFF[bkt * NB3];
    int e = (bkt == NBUCK - 1) ? N_EDGES : OFF[(bkt + 1) * NB3];
    __shared__ int cnt[128];
    if (threadIdx.x < 128) cnt[threadIdx.x] = 0;
    __syncthreads();
    for (int i = s + threadIdx.x; i < e; i += 256)
        atomicAdd(&cnt[binned[i] >> 17], 1);
    __syncthreads();
    int n = (bkt << BSHIFT) + threadIdx.x;
    if (threadIdx.x < 128 && n < N_NODES) {
        degs[n] = cnt[threadIdx.x];
        dinv[n] = rsqrtf((float)cnt[threadIdx.x] + 1.0f);
    }
}

// ---- xws = (x @ W_gcn) * dinv, output bf16 -------------------------------
__global__ __launch_bounds__(256) void k_gemm(const float* __restrict__ x,
                                              const float* __restrict__ Wg,
                                              const float* __restrict__ dinv,
                                              unsigned short* __restrict__ xws) {
    __shared__ float wl[IN_DIM * HID_DIM];  // 32 KB
    for (int i = threadIdx.x; i < IN_DIM * HID_DIM; i += 256) wl[i] = Wg[i];
    __syncthreads();

    int wave = threadIdx.x >> 6;
    int lane = threadIdx.x & 63;
    int node0 = blockIdx.x * 32 + wave * 8;   // 100000 = 3125 * 32, exact

    const int* xi = (const int*)x;
    int xr[8][2];
#pragma unroll
    for (int m = 0; m < 8; m++) {
#pragma unroll
        for (int h = 0; h < 2; h++)
            xr[m][h] = xi[(size_t)(node0 + m) * IN_DIM + h * 64 + lane];
    }

    float acc[8] = {0.f, 0.f, 0.f, 0.f, 0.f, 0.f, 0.f, 0.f};
#pragma unroll
    for (int k = 0; k < 64; k++) {
        float wv = wl[k * HID_DIM + lane];
#pragma unroll
        for (int m = 0; m < 8; m++)
            acc[m] += uaf(__builtin_amdgcn_readlane(xr[m][0], k)) * wv;
    }
#pragma unroll
    for (int k = 0; k < 64; k++) {
        float wv = wl[(64 + k) * HID_DIM + lane];
#pragma unroll
        for (int m = 0; m < 8; m++)
            acc[m] += uaf(__builtin_amdgcn_readlane(xr[m][1], k)) * wv;
    }

#pragma unroll
    for (int m = 0; m < 8; m++) {
        float dn = dinv[node0 + m];
        xws[(size_t)(node0 + m) * HID_DIM + lane] = f2bf(acc[m] * dn);
    }
}

// ---- fused local-CSR build + gather-aggregate + ReLU + mean-pool ---------
// One block per bucket (128 dest nodes). Edge ids live in LDS, 4-aligned per
// node (pads -> ZERO_ROW). Wave w handles local nodes [w*32, w*32+32).
// dinv recomputed from LDS degs. Pool: per-wave LDS slots over the <=8
// graphs this 128-node window can span (batch sorted), one global atomic
// per (slot, col) per block at the end.
__global__ __launch_bounds__(256) void k_aggrf(const unsigned short* __restrict__ xws,
                                               const int* __restrict__ binned,
                                               const int* __restrict__ OFF,
                                               const int* __restrict__ degs,
                                               const int* __restrict__ batch,
                                               const float* __restrict__ bg,
                                               float* __restrict__ gsum) {
    int bkt = blockIdx.x;
    int s = OFF[bkt * NB3];
    int e = (bkt == NBUCK - 1) ? N_EDGES : OFF[(bkt + 1) * NB3];
    int m = e - s;
    int nbase = bkt << BSHIFT;
    int nnodes = N_NODES - nbase; if (nnodes > 128) nnodes = 128;

    __shared__ int cnt[128];
    __shared__ int lptr[129];
    __shared__ int cur[128];
    __shared__ int sb[128];
    __shared__ alignas(16) int srt[LDS_E];
    __shared__ float pool[4][8][64];   // [wave][graph-slot][col]

    if (threadIdx.x < 128) {
        int n = nbase + threadIdx.x;
        cnt[threadIdx.x] = (threadIdx.x < nnodes) ? degs[n] : 0;
        sb[threadIdx.x]  = (threadIdx.x < nnodes) ? batch[n] : 0;
        cur[threadIdx.x] = 0;
    }
    for (int t = threadIdx.x; t < 4 * 8 * 64; t += 256)
        ((float*)pool)[t] = 0.f;
    __syncthreads();

    if (threadIdx.x == 0) {           // 4-aligned exclusive scan of counts
        int run = 0;
        for (int i = 0; i < 128; i++) { lptr[i] = run; run += (cnt[i] + 3) & ~3; }
        lptr[128] = run;
    }
    __syncthreads();
    int tot = lptr[128];              // <= m + 384 << LDS_E
    for (int i = threadIdx.x; i < tot; i += 256) srt[i] = ZERO_ROW;
    __syncthreads();
    for (int i = threadIdx.x; i < m; i += 256) {
        int pk = binned[s + i];
        int nid = pk >> 17;
        int rk = atomicAdd(&cur[nid], 1);
        int pos = lptr[nid] + rk;
        if (pos < LDS_E) srt[pos] = pk & 0x1FFFF;
    }
    __syncthreads();

    int wave = threadIdx.x >> 6;
    int lane = threadIdx.x & 63;
    float bgl = bg[lane];
    int g0 = sb[0];

    for (int k = 0; k < 32; k++) {
        int ln = wave * 32 + k;
        if (ln >= nnodes) break;
        int n = nbase + ln;
        int s0 = lptr[ln], e0 = lptr[ln + 1];
        float a0 = bf2f(xws[(size_t)n * HID_DIM + lane]);   // self term
        float a1 = 0.f, a2 = 0.f, a3 = 0.f;
        for (int i = s0; i < e0; i += 4) {
            int4 r4 = *reinterpret_cast<const int4*>(&srt[i]);  // broadcast b128
            a0 += bf2f(xws[(size_t)r4.x * HID_DIM + lane]);
            a1 += bf2f(xws[(size_t)r4.y * HID_DIM + lane]);
            a2 += bf2f(xws[(size_t)r4.z * HID_DIM + lane]);
            a3 += bf2f(xws[(size_t)r4.w * HID_DIM + lane]);
        }
        float dn = rsqrtf((float)cnt[ln] + 1.0f);
        float val = fmaxf(((a0 + a1) + (a2 + a3)) * dn + bgl, 0.f);
        int slot = sb[ln] - g0;
        if (slot < 8) {
            pool[wave][slot][lane] += val;
        } else {                                  // statistically impossible
            atomicAdd(&gsum[sb[ln] * HID_DIM + lane], val);
        }
    }
    __syncthreads();

    for (int t = threadIdx.x; t < 8 * 64; t += 256) {
        int slot = t >> 6, j = t & 63;
        float v = pool[0][slot][j] + pool[1][slot][j]
                + pool[2][slot][j] + pool[3][slot][j];
        if (v != 0.f) atomicAdd(&gsum[(g0 + slot) * HID_DIM + j], v);
    }
}

// ---- divide by counts + MLP + sigmoid (one wave per graph) ---------------
__device__ inline int lower_bound_i(const int* __restrict__ a, int n, int v) {
    int lo = 0, hi = n;
    while (lo < hi) {
        int mid = (lo + hi) >> 1;
        if (a[mid] < v) lo = mid + 1; else hi = mid;
    }
    return lo;
}

__global__ __launch_bounds__(64) void k_mlp(const float* __restrict__ gsum,
                                            const int* __restrict__ batch,
                                            const float* __restrict__ W1,
                                            const float* __restrict__ b1,
                                            const float* __restrict__ W2,
                                            const float* __restrict__ b2,
                                            float* __restrict__ out) {
    int g = blockIdx.x;
    int j = threadIdx.x;
    int start = lower_bound_i(batch, N_NODES, g);
    int end   = lower_bound_i(batch, N_NODES, g + 1);
    float cnt = fmaxf((float)(end - start), 1.0f);

    __shared__ float gs[64];
    __shared__ float hs[64];
    gs[j] = gsum[g * 64 + j] / cnt;
    __syncthreads();

    float h = b1[j];
    for (int k = 0; k < 64; k++) h += gs[k] * W1[k * 64 + j];
    hs[j] = fmaxf(h, 0.f);
    __syncthreads();

    if (j < OUT_DIM) {
        float o = b2[j];
        for (int k = 0; k < 64; k++) o += hs[k] * W2[k * OUT_DIM + j];
        out[g * OUT_DIM + j] = 1.f / (1.f + expf(-o));
    }
}

extern "C" void kernel_launch(void* const* d_in, const int* in_sizes, int n_in,
                              void* d_out, int out_size, void* d_ws, size_t ws_size,
                              hipStream_t stream) {
    const float* x   = (const float*)d_in[0];
    const int* eidx  = (const int*)d_in[1];
    const int* batch = (const int*)d_in[2];
    const float* Wg  = (const float*)d_in[3];
    const float* bg  = (const float*)d_in[4];
    const float* W1  = (const float*)d_in[5];
    const float* b1  = (const float*)d_in[6];
    const float* W2  = (const float*)d_in[7];
    const float* b2  = (const float*)d_in[8];
    float* out = (float*)d_out;

    // workspace layout (~30 MB)
    char* w = (char*)d_ws;
    unsigned short* xws = (unsigned short*)w;   w += (size_t)(N_NODES + 1) * HID_DIM * 2; // 12.8 MB
    int*   binned  = (int*)w;                   w += (size_t)N_EDGES * 4;                 // 12.8 MB
    int*   H       = (int*)w;                   w += (size_t)NBUCK * NB3 * 4;             // 1.6 MB
    int*   OFF     = (int*)w;                   w += (size_t)NBUCK * NB3 * 4;             // 1.6 MB
    int*   bsum    = (int*)w;                   w += NSB * 4;
    int*   degs    = (int*)w;                   w += N_NODES * 4;
    float* dinv    = (float*)w;                 w += N_NODES * 4;
    float* gsum    = (float*)w;                 w += N_GRAPHS * HID_DIM * 4;              // 131 KB

    const int* rowp = eidx;             // edge_index[0] (sources)
    const int* colp = eidx + N_EDGES;   // edge_index[1] (destinations)

    hipMemsetAsync(gsum, 0, N_GRAPHS * HID_DIM * sizeof(float), stream);
    hipMemsetAsync(xws + (size_t)ZERO_ROW * HID_DIM, 0, HID_DIM * 2, stream);

    k_hist<<<NB3, 256, 0, stream>>>(colp, H);
    k_scan_a<<<NSB, 1024, 0, stream>>>(H, OFF, bsum);
    k_scan_b<<<NSB, 1024, 0, stream>>>(OFF, bsum);
    k_scatter<<<NB3, 256, 0, stream>>>(rowp, colp, OFF, binned);
    k_deg<<<NBUCK, 256, 0, stream>>>(binned, OFF, degs, dinv);
    k_gemm<<<N_NODES / 32, 256, 0, stream>>>(x, Wg, dinv, xws);
    k_aggrf<<<NBUCK, 256, 0, stream>>>(xws, binned, OFF, degs, batch, bg, gsum);
    k_mlp<<<N_GRAPHS, 64, 0, stream>>>(gsum, batch, W1, b1, W2, b2, out);
}

// Round 7
// 299.500 us; speedup vs baseline: 10.7119x; 1.2173x over previous
//
#include <hip/hip_runtime.h>

#define N_NODES 100000
#define N_EDGES 3200000
#define IN_DIM 128
#define HID_DIM 64
#define OUT_DIM 2
#define N_GRAPHS 512

#define BSHIFT 7
#define NBUCK 782          // ceil(100000/128)
#define NB3 512            // blocks in hist/scatter passes
#define EPB 6250           // edges per block (512*6250 = 3.2M exact)
#define NSB 391            // scan blocks: 782*512/1024 = 391 exact
#define LDS_E2 3072        // per-half-bucket edge capacity (mean ~2050+pad<=448, 12+ sd slack)
#define ZERO_ROW N_NODES   // all-zero xws row used for alignment padding

__device__ inline float uaf(unsigned int u) {
    union { unsigned int i; float f; } v; v.i = u; return v.f;
}
__device__ inline unsigned short f2bf(float f) {
    union { float f; unsigned int i; } v; v.f = f;
    unsigned int r = v.i + 0x7fffu + ((v.i >> 16) & 1u);
    return (unsigned short)(r >> 16);
}
__device__ inline float bf2f(unsigned short u) {
    union { unsigned int i; float f; } v; v.i = ((unsigned int)u) << 16; return v.f;
}

// ---- pass 1: per-block LDS histogram over 782 coarse buckets -------------
__global__ __launch_bounds__(256) void k_hist(const int* __restrict__ col,
                                              int* __restrict__ H) {
    __shared__ int h[NBUCK];
    for (int i = threadIdx.x; i < NBUCK; i += 256) h[i] = 0;
    __syncthreads();
    int b = blockIdx.x;
    int s = b * EPB, e = s + EPB;
    for (int i = s + threadIdx.x; i < e; i += 256)
        atomicAdd(&h[col[i] >> BSHIFT], 1);
    __syncthreads();
    for (int i = threadIdx.x; i < NBUCK; i += 256)
        H[i * NB3 + b] = h[i];                    // bucket-major for the scan
}

// ---- pass 2a: local exclusive scan of the 400384-entry matrix ------------
__global__ __launch_bounds__(1024) void k_scan_a(const int* __restrict__ H,
                                                 int* __restrict__ OFF,
                                                 int* __restrict__ bsum) {
    __shared__ int lds[1024];
    int i = blockIdx.x * 1024 + threadIdx.x;
    int v = H[i];
    lds[threadIdx.x] = v;
    __syncthreads();
    for (int off = 1; off < 1024; off <<= 1) {
        int t = (threadIdx.x >= off) ? lds[threadIdx.x - off] : 0;
        __syncthreads();
        lds[threadIdx.x] += t;
        __syncthreads();
    }
    OFF[i] = lds[threadIdx.x] - v;
    if (threadIdx.x == 1023) bsum[blockIdx.x] = lds[1023];
}

// ---- pass 2b: finalize with block-sum prefix ------------------------------
__global__ __launch_bounds__(1024) void k_scan_b(int* __restrict__ OFF,
                                                 const int* __restrict__ bsum) {
    __shared__ int ls[NSB];
    for (int i = threadIdx.x; i < NSB; i += 1024) ls[i] = bsum[i];
    __syncthreads();
    if (threadIdx.x == 0) {
        int run = 0;
        for (int b = 0; b < NSB; b++) { int t = ls[b]; ls[b] = run; run += t; }
    }
    __syncthreads();
    int i = blockIdx.x * 1024 + threadIdx.x;
    OFF[i] += ls[blockIdx.x];
}

// ---- pass 3: scatter packed edges into bucket-sorted order ---------------
// pk = (col & 127) << 17 | row   (row < 2^17). Per block, per bucket the
// writes are CONSECUTIVE slots -> write amplification collapses.
__global__ __launch_bounds__(256) void k_scatter(const int* __restrict__ row,
                                                 const int* __restrict__ col,
                                                 const int* __restrict__ OFF,
                                                 int* __restrict__ binned) {
    __shared__ int lofs[NBUCK];
    __shared__ int cur[NBUCK];
    int b = blockIdx.x;
    for (int i = threadIdx.x; i < NBUCK; i += 256) {
        lofs[i] = OFF[i * NB3 + b];
        cur[i] = 0;
    }
    __syncthreads();
    int s = b * EPB, e = s + EPB;
    for (int i = s + threadIdx.x; i < e; i += 256) {
        int c = col[i];
        int r = row[i];
        int bk = c >> BSHIFT;
        int rk = atomicAdd(&cur[bk], 1);
        binned[lofs[bk] + rk] = ((c & 127) << 17) | r;
    }
}

// ---- per-node degree + dinv from the binned array (LDS-local counts) -----
__global__ __launch_bounds__(256) void k_deg(const int* __restrict__ binned,
                                             const int* __restrict__ OFF,
                                             int* __restrict__ degs,
                                             float* __restrict__ dinv) {
    int bkt = blockIdx.x;
    int s = OFF[bkt * NB3];
    int e = (bkt == NBUCK - 1) ? N_EDGES : OFF[(bkt + 1) * NB3];
    __shared__ int cnt[128];
    if (threadIdx.x < 128) cnt[threadIdx.x] = 0;
    __syncthreads();
    for (int i = s + threadIdx.x; i < e; i += 256)
        atomicAdd(&cnt[binned[i] >> 17], 1);
    __syncthreads();
    int n = (bkt << BSHIFT) + threadIdx.x;
    if (threadIdx.x < 128 && n < N_NODES) {
        degs[n] = cnt[threadIdx.x];
        dinv[n] = rsqrtf((float)cnt[threadIdx.x] + 1.0f);
    }
}

// ---- xws = (x @ W_gcn) * dinv, output bf16 -------------------------------
__global__ __launch_bounds__(256) void k_gemm(const float* __restrict__ x,
                                              const float* __restrict__ Wg,
                                              const float* __restrict__ dinv,
                                              unsigned short* __restrict__ xws) {
    __shared__ float wl[IN_DIM * HID_DIM];  // 32 KB
    for (int i = threadIdx.x; i < IN_DIM * HID_DIM; i += 256) wl[i] = Wg[i];
    __syncthreads();

    int wave = threadIdx.x >> 6;
    int lane = threadIdx.x & 63;
    int node0 = blockIdx.x * 32 + wave * 8;   // 100000 = 3125 * 32, exact

    const int* xi = (const int*)x;
    int xr[8][2];
#pragma unroll
    for (int m = 0; m < 8; m++) {
#pragma unroll
        for (int h = 0; h < 2; h++)
            xr[m][h] = xi[(size_t)(node0 + m) * IN_DIM + h * 64 + lane];
    }

    float acc[8] = {0.f, 0.f, 0.f, 0.f, 0.f, 0.f, 0.f, 0.f};
#pragma unroll
    for (int k = 0; k < 64; k++) {
        float wv = wl[k * HID_DIM + lane];
#pragma unroll
        for (int m = 0; m < 8; m++)
            acc[m] += uaf(__builtin_amdgcn_readlane(xr[m][0], k)) * wv;
    }
#pragma unroll
    for (int k = 0; k < 64; k++) {
        float wv = wl[(64 + k) * HID_DIM + lane];
#pragma unroll
        for (int m = 0; m < 8; m++)
            acc[m] += uaf(__builtin_amdgcn_readlane(xr[m][1], k)) * wv;
    }

#pragma unroll
    for (int m = 0; m < 8; m++) {
        float dn = dinv[node0 + m];
        xws[(size_t)(node0 + m) * HID_DIM + lane] = f2bf(acc[m] * dn);
    }
}

// ---- fused local-CSR build + gather-aggregate + ReLU + mean-pool ---------
// TWO blocks per bucket; each handles 64 dest nodes (filters the bucket's
// binned range). Edge ids in LDS, 8-aligned per node (pads -> ZERO_ROW).
// Wave w handles local nodes [w*16, w*16+16). 8 accumulator chains = 8
// outstanding gathers/wave. Pool via per-wave LDS slots (4 graphs/64-node
// window whp; fallback atomic).
__global__ __launch_bounds__(256) void k_aggrf(const unsigned short* __restrict__ xws,
                                               const int* __restrict__ binned,
                                               const int* __restrict__ OFF,
                                               const int* __restrict__ degs,
                                               const int* __restrict__ batch,
                                               const float* __restrict__ bg,
                                               float* __restrict__ gsum) {
    int bkt = blockIdx.x >> 1;
    int half = blockIdx.x & 1;
    int nbase = (bkt << BSHIFT) + half * 64;
    if (nbase >= N_NODES) return;                 // uniform exit (last bucket)
    int nnodes = N_NODES - nbase; if (nnodes > 64) nnodes = 64;
    int s = OFF[bkt * NB3];
    int e = (bkt == NBUCK - 1) ? N_EDGES : OFF[(bkt + 1) * NB3];
    int m = e - s;

    __shared__ int cnt[64];
    __shared__ int lptr[65];
    __shared__ int cur[64];
    __shared__ int sb[64];
    __shared__ alignas(16) int srt[LDS_E2];
    __shared__ float pool[4][4][64];   // [wave][graph-slot][col]

    if (threadIdx.x < 64) {
        int n = nbase + threadIdx.x;
        cnt[threadIdx.x] = (threadIdx.x < nnodes) ? degs[n] : 0;
        sb[threadIdx.x]  = (threadIdx.x < nnodes) ? batch[n] : 0;
        cur[threadIdx.x] = 0;
    }
    for (int t = threadIdx.x; t < 4 * 4 * 64; t += 256)
        ((float*)pool)[t] = 0.f;
    __syncthreads();

    if (threadIdx.x == 0) {           // 8-aligned exclusive scan of counts
        int run = 0;
        for (int i = 0; i < 64; i++) { lptr[i] = run; run += (cnt[i] + 7) & ~7; }
        lptr[64] = run;
    }
    __syncthreads();
    int tot = lptr[64];
    for (int i = threadIdx.x; i < tot; i += 256) srt[i] = ZERO_ROW;
    __syncthreads();
    int hb = half << 6;
    for (int i = threadIdx.x; i < m; i += 256) {
        int pk = binned[s + i];
        int local = (pk >> 17) - hb;
        if ((unsigned)local < 64u) {
            int rk = atomicAdd(&cur[local], 1);
            int pos = lptr[local] + rk;
            if (pos < LDS_E2) srt[pos] = pk & 0x1FFFF;
        }
    }
    __syncthreads();

    int wave = threadIdx.x >> 6;
    int lane = threadIdx.x & 63;
    float bgl = bg[lane];
    int g0 = sb[0];

    for (int k = 0; k < 16; k++) {
        int ln = wave * 16 + k;
        if (ln >= nnodes) break;
        int n = nbase + ln;
        int s0 = lptr[ln], e0 = lptr[ln + 1];
        float a0 = bf2f(xws[(size_t)n * HID_DIM + lane]);   // self term
        float a1 = 0.f, a2 = 0.f, a3 = 0.f;
        float a4 = 0.f, a5 = 0.f, a6 = 0.f, a7 = 0.f;
        for (int i = s0; i < e0; i += 8) {                  // e0-s0 % 8 == 0
            int4 ra = *reinterpret_cast<const int4*>(&srt[i]);
            int4 rb = *reinterpret_cast<const int4*>(&srt[i + 4]);
            a0 += bf2f(xws[(size_t)ra.x * HID_DIM + lane]);
            a1 += bf2f(xws[(size_t)ra.y * HID_DIM + lane]);
            a2 += bf2f(xws[(size_t)ra.z * HID_DIM + lane]);
            a3 += bf2f(xws[(size_t)ra.w * HID_DIM + lane]);
            a4 += bf2f(xws[(size_t)rb.x * HID_DIM + lane]);
            a5 += bf2f(xws[(size_t)rb.y * HID_DIM + lane]);
            a6 += bf2f(xws[(size_t)rb.z * HID_DIM + lane]);
            a7 += bf2f(xws[(size_t)rb.w * HID_DIM + lane]);
        }
        float dn = rsqrtf((float)cnt[ln] + 1.0f);
        float val = fmaxf((((a0 + a1) + (a2 + a3)) + ((a4 + a5) + (a6 + a7))) * dn + bgl, 0.f);
        int slot = sb[ln] - g0;
        if (slot < 4) {
            pool[wave][slot][lane] += val;
        } else {                                  // statistically impossible
            atomicAdd(&gsum[sb[ln] * HID_DIM + lane], val);
        }
    }
    __syncthreads();

    for (int t = threadIdx.x; t < 4 * 64; t += 256) {
        int slot = t >> 6, j = t & 63;
        float v = pool[0][slot][j] + pool[1][slot][j]
                + pool[2][slot][j] + pool[3][slot][j];
        if (v != 0.f) atomicAdd(&gsum[(g0 + slot) * HID_DIM + j], v);
    }
}

// ---- divide by counts + MLP + sigmoid (one wave per graph) ---------------
__device__ inline int lower_bound_i(const int* __restrict__ a, int n, int v) {
    int lo = 0, hi = n;
    while (lo < hi) {
        int mid = (lo + hi) >> 1;
        if (a[mid] < v) lo = mid + 1; else hi = mid;
    }
    return lo;
}

__global__ __launch_bounds__(64) void k_mlp(const float* __restrict__ gsum,
                                            const int* __restrict__ batch,
                                            const float* __restrict__ W1,
                                            const float* __restrict__ b1,
                                            const float* __restrict__ W2,
                                            const float* __restrict__ b2,
                                            float* __restrict__ out) {
    int g = blockIdx.x;
    int j = threadIdx.x;
    int start = lower_bound_i(batch, N_NODES, g);
    int end   = lower_bound_i(batch, N_NODES, g + 1);
    float cnt = fmaxf((float)(end - start), 1.0f);

    __shared__ float gs[64];
    __shared__ float hs[64];
    gs[j] = gsum[g * 64 + j] / cnt;
    __syncthreads();

    float h = b1[j];
    for (int k = 0; k < 64; k++) h += gs[k] * W1[k * 64 + j];
    hs[j] = fmaxf(h, 0.f);
    __syncthreads();

    if (j < OUT_DIM) {
        float o = b2[j];
        for (int k = 0; k < 64; k++) o += hs[k] * W2[k * OUT_DIM + j];
        out[g * OUT_DIM + j] = 1.f / (1.f + expf(-o));
    }
}

extern "C" void kernel_launch(void* const* d_in, const int* in_sizes, int n_in,
                              void* d_out, int out_size, void* d_ws, size_t ws_size,
                              hipStream_t stream) {
    const float* x   = (const float*)d_in[0];
    const int* eidx  = (const int*)d_in[1];
    const int* batch = (const int*)d_in[2];
    const float* Wg  = (const float*)d_in[3];
    const float* bg  = (const float*)d_in[4];
    const float* W1  = (const float*)d_in[5];
    const float* b1  = (const float*)d_in[6];
    const float* W2  = (const float*)d_in[7];
    const float* b2  = (const float*)d_in[8];
    float* out = (float*)d_out;

    // workspace layout (~30 MB)
    char* w = (char*)d_ws;
    unsigned short* xws = (unsigned short*)w;   w += (size_t)(N_NODES + 1) * HID_DIM * 2; // 12.8 MB
    int*   binned  = (int*)w;                   w += (size_t)N_EDGES * 4;                 // 12.8 MB
    int*   H       = (int*)w;                   w += (size_t)NBUCK * NB3 * 4;             // 1.6 MB
    int*   OFF     = (int*)w;                   w += (size_t)NBUCK * NB3 * 4;             // 1.6 MB
    int*   bsum    = (int*)w;                   w += NSB * 4;
    int*   degs    = (int*)w;                   w += N_NODES * 4;
    float* dinv    = (float*)w;                 w += N_NODES * 4;
    float* gsum    = (float*)w;                 w += N_GRAPHS * HID_DIM * 4;              // 131 KB

    const int* rowp = eidx;             // edge_index[0] (sources)
    const int* colp = eidx + N_EDGES;   // edge_index[1] (destinations)

    hipMemsetAsync(gsum, 0, N_GRAPHS * HID_DIM * sizeof(float), stream);
    hipMemsetAsync(xws + (size_t)ZERO_ROW * HID_DIM, 0, HID_DIM * 2, stream);

    k_hist<<<NB3, 256, 0, stream>>>(colp, H);
    k_scan_a<<<NSB, 1024, 0, stream>>>(H, OFF, bsum);
    k_scan_b<<<NSB, 1024, 0, stream>>>(OFF, bsum);
    k_scatter<<<NB3, 256, 0, stream>>>(rowp, colp, OFF, binned);
    k_deg<<<NBUCK, 256, 0, stream>>>(binned, OFF, degs, dinv);
    k_gemm<<<N_NODES / 32, 256, 0, stream>>>(x, Wg, dinv, xws);
    k_aggrf<<<2 * NBUCK, 256, 0, stream>>>(xws, binned, OFF, degs, batch, bg, gsum);
    k_mlp<<<N_GRAPHS, 64, 0, stream>>>(gsum, batch, W1, b1, W2, b2, out);
}